// Round 17
// baseline (146.215 us; speedup 1.0000x reference)
//
#include <hip/hip_runtime.h>
#include <math.h>

#define NEG_SLOPE 0.2f
#define CAP 8192      // padded bucket capacity (mean fill 4096, sd ~64)

typedef _Float16 half8 __attribute__((ext_vector_type(8)));
typedef _Float16 half4v __attribute__((ext_vector_type(4)));
typedef float float4v __attribute__((ext_vector_type(4)));

// ---------------------------------------------------- setup: prep_wt + cursor
__global__ void setup_misc(const float* __restrict__ W0, const float* __restrict__ W1,
                           const float* __restrict__ Wp1, const float* __restrict__ Wp2,
                           _Float16* __restrict__ W0T, _Float16* __restrict__ W1T,
                           _Float16* __restrict__ Wp1T, _Float16* __restrict__ Wp2T,
                           int* __restrict__ cursor, int NB) {
    const int tid = threadIdx.x;
    if (blockIdx.x == 4) {
        for (int t = tid; t < NB; t += 256) cursor[t] = t * CAP;
        return;
    }
    __shared__ float lds[128 * 64];
    const float* src; _Float16* dstp; int K;
    switch (blockIdx.x) {
        case 0: src = W0;  dstp = W0T;  K = 128; break;
        case 1: src = W1;  dstp = W1T;  K = 64;  break;
        case 2: src = Wp1; dstp = Wp1T; K = 64;  break;
        default: src = Wp2; dstp = Wp2T; K = 64; break;
    }
    for (int i = tid; i < K * 64; i += 256) lds[i] = src[i];
    __syncthreads();
    for (int i = tid; i < K * 64; i += 256) {
        int n = i / K, k = i % K;
        dstp[i] = (_Float16)lds[k * 64 + n];
    }
}

// ------------- bin edges into bucket regions, LDS-staged coalesced writes ----
__global__ void bin_staged(const int* __restrict__ src, const int* __restrict__ dst,
                           int* __restrict__ cursor, unsigned int* __restrict__ packed,
                           int E, int NB) {
    __shared__ unsigned int sval[4096];
    __shared__ unsigned int saddr[4096];
    __shared__ int h[512], hcur[512], gb[512];
    __shared__ int stot;
    const int tid = threadIdx.x;
    if (tid == 0) stot = 0;
    for (int t = tid; t < NB; t += 256) h[t] = 0;
    __syncthreads();
    const int base = blockIdx.x * 4096;
    const int lim = min(base + 4096, E);
    int dreg[16], sreg[16];
    int cnt = 0;
    for (int i = base + tid; i < lim; i += 256) {
        dreg[cnt] = dst[i];
        sreg[cnt] = src[i];
        ++cnt;
    }
    for (int k = 0; k < cnt; ++k) atomicAdd(&h[dreg[k] >> 8], 1);
    __syncthreads();
    for (int t = tid; t < NB; t += 256) {
        int c = h[t];
        if (c) {
            int l = atomicAdd(&stot, c);          // block-local region (order-free)
            hcur[t] = l;
            gb[t] = atomicAdd(&cursor[t], c) - l; // gaddr = gb[bucket] + pos
        }
    }
    __syncthreads();
    for (int k = 0; k < cnt; ++k) {
        const int d = dreg[k];
        const int b = d >> 8;
        const int pos = atomicAdd(&hcur[b], 1);
        sval[pos] = ((unsigned int)(d & 255) << 24) | (unsigned int)sreg[k];
        saddr[pos] = (unsigned int)(gb[b] + pos);
    }
    __syncthreads();
    const int tot = stot;
    for (int j = tid; j < tot; j += 256)
        packed[saddr[j]] = sval[j];               // consecutive j -> coalesced runs
}

// ---------------- fused: bucket_sort (blocks<NB) | gemm0 (independent work)
__device__ __forceinline__ void sort_body(const unsigned int* __restrict__ packed,
                                          const int* __restrict__ cursor,
                                          int* __restrict__ csr, int2* __restrict__ rr,
                                          int N, int b) {
    __shared__ int hist[256], cur[256];
    __shared__ int wsum[4], woff[4];
    const int tid = threadIdx.x, wid = tid >> 6, lane = tid & 63;
    const int beg = b * CAP;
    const int end = cursor[b];                 // fill end of this bucket
    hist[tid] = 0;
    __syncthreads();
    for (int i = beg + tid; i < end; i += 256)
        atomicAdd(&hist[packed[i] >> 24], 1);
    __syncthreads();
    int v = hist[tid];
    int x = v;
    #pragma unroll
    for (int off = 1; off < 64; off <<= 1) {
        int t = __shfl_up(x, off);
        if (lane >= off) x += t;
    }
    if (lane == 63) wsum[wid] = x;
    __syncthreads();
    if (tid == 0) {
        int acc = 0;
        #pragma unroll
        for (int w = 0; w < 4; ++w) { woff[w] = acc; acc += wsum[w]; }
    }
    __syncthreads();
    int excl = woff[wid] + x - v;
    int node = (b << 8) + tid;
    if (node < N) rr[node] = make_int2(beg + excl, v);
    cur[tid] = excl;
    __syncthreads();
    for (int i = beg + tid; i < end; i += 256) {
        unsigned int p = packed[i];
        int pos = atomicAdd(&cur[p >> 24], 1);
        csr[beg + pos] = (int)(p & 0xFFFFFFu);
    }
}

__device__ __forceinline__ void gemm0_body(const float* __restrict__ X,
                                           const _Float16* __restrict__ WT,
                                           const float* __restrict__ alw,
                                           const float* __restrict__ arw,
                                           _Float16* __restrict__ XH,
                                           float* __restrict__ AL, float* __restrict__ AR,
                                           int N, int bid) {
    const int wid = threadIdx.x >> 6, lane = threadIdx.x & 63;
    const int rowbase = bid * 64 + wid * 16;
    const int idx16 = lane & 15;
    const int g = lane >> 4;
    const int mrow = rowbase + idx16;
    const bool mvalid = (mrow < N);

    float4v acc[4];
    #pragma unroll
    for (int n = 0; n < 4; ++n) acc[n] = float4v{0.f, 0.f, 0.f, 0.f};

    #pragma unroll
    for (int ks = 0; ks < 4; ++ks) {           // K = 128
        const int k0 = ks * 32 + g * 8;
        half8 a = {};
        if (mvalid) {
            const float* xp = X + (size_t)mrow * 128 + k0;
            float4v lo = *reinterpret_cast<const float4v*>(xp);
            float4v hi = *reinterpret_cast<const float4v*>(xp + 4);
            #pragma unroll
            for (int i = 0; i < 4; ++i) {
                a[i] = (_Float16)lo[i];
                a[i + 4] = (_Float16)hi[i];
            }
        }
        #pragma unroll
        for (int n = 0; n < 4; ++n) {
            const half8 b = *reinterpret_cast<const half8*>(WT + (size_t)(n * 16 + idx16) * 128 + k0);
            acc[n] = __builtin_amdgcn_mfma_f32_16x16x32_f16(a, b, acc[n], 0, 0, 0);
        }
    }

    float alv[4], arv[4];
    #pragma unroll
    for (int n = 0; n < 4; ++n) { alv[n] = alw[n * 16 + idx16]; arv[n] = arw[n * 16 + idx16]; }
    #pragma unroll
    for (int r = 0; r < 4; ++r) {
        const int row = rowbase + g * 4 + r;
        if (row < N) {
            float pl = 0.f, pr = 0.f;
            #pragma unroll
            for (int n = 0; n < 4; ++n) {
                float vv = acc[n][r];
                XH[(size_t)row * 64 + n * 16 + idx16] = (_Float16)vv;
                pl = fmaf(vv, alv[n], pl);
                pr = fmaf(vv, arv[n], pr);
            }
            pl += __shfl_xor(pl, 1); pr += __shfl_xor(pr, 1);
            pl += __shfl_xor(pl, 2); pr += __shfl_xor(pr, 2);
            pl += __shfl_xor(pl, 4); pr += __shfl_xor(pr, 4);
            pl += __shfl_xor(pl, 8); pr += __shfl_xor(pr, 8);
            if (idx16 == 0) { AL[row] = pl; AR[row] = pr; }
        }
    }
}

__global__ void sort_and_gemm0(const unsigned int* __restrict__ packed,
                               const int* __restrict__ cursor,
                               int* __restrict__ csr, int2* __restrict__ rr,
                               const float* __restrict__ X,
                               const _Float16* __restrict__ W0T,
                               const float* __restrict__ alw, const float* __restrict__ arw,
                               _Float16* __restrict__ XH0, float* __restrict__ AL0,
                               float* __restrict__ AR0, int N, int NB) {
    if ((int)blockIdx.x < NB)
        sort_body(packed, cursor, csr, rr, N, blockIdx.x);
    else
        gemm0_body(X, W0T, alw, arw, XH0, AL0, AR0, N, blockIdx.x - NB);
}

// ============================== fused aggregate -> relu -> GEMM kernels ====
// Block = 128 threads (2 waves), 16 nodes: one node per 8-LANE group.
// 16 edges per iteration: lane l owns edges cbeg+2l, cbeg+2l+1 (2 csr loads,
// 2 AL gathers, 2 exps), then a fixed-bound j-loop issues 16 XH-row gathers
// (half8, 16B) back-to-back -> 2x in-flight rows AND 35% fewer serial chunk
// iterations vs R16's 8-edge chunks; zero new exec-mask divergence.
// Result (relu'd, normalized, fp16) -> LDS ts[16][64], XOR-swizzled. One
// barrier (2 waves); wave 0 runs the GEMM tail, wave 1 returns.

__device__ __forceinline__ void agg_phase(const int2* __restrict__ rr,
                                          const int* __restrict__ csr,
                                          const float* __restrict__ ALp,
                                          const float* __restrict__ ARp,
                                          const _Float16* __restrict__ XHp,
                                          _Float16* ts, int nb, int N) {
    const int tid = threadIdx.x;
    const int l = tid & 7, grp = tid >> 3;       // 16 groups of 8 lanes
    const int node = nb + grp;
    float accv[8] = {0.f, 0.f, 0.f, 0.f, 0.f, 0.f, 0.f, 0.f};
    float inv = 0.0f;
    if (node < N) {
        const int2 r = rr[node];
        const int beg = r.x, end = r.x + r.y;
        const float ar = ARp[node];
        float s = 0.f;
        for (int cbeg = beg; cbeg < end; cbeg += 16) {
            const int e0 = cbeg + 2 * l;
            const int e1 = e0 + 1;
            const bool v0 = (e0 < end), v1 = (e1 < end);
            const int s0 = v0 ? csr[e0] : 0;
            const int s1 = v1 ? csr[e1] : 0;
            float a0 = ALp[s0] + ar;
            a0 = (a0 >= 0.f) ? a0 : NEG_SLOPE * a0;
            float a1 = ALp[s1] + ar;
            a1 = (a1 >= 0.f) ? a1 : NEG_SLOPE * a1;
            const float ex0 = v0 ? __expf(a0) : 0.f;
            const float ex1 = v1 ? __expf(a1) : 0.f;
            s += ex0 + ex1;
            #pragma unroll
            for (int j = 0; j < 8; ++j) {
                const float w0 = __shfl(ex0, j, 8);
                const int   i0 = __shfl(s0, j, 8);
                const float w1 = __shfl(ex1, j, 8);
                const int   i1 = __shfl(s1, j, 8);
                const half8 h0 = *reinterpret_cast<const half8*>(XHp + (size_t)i0 * 64 + l * 8);
                const half8 h1 = *reinterpret_cast<const half8*>(XHp + (size_t)i1 * 64 + l * 8);
                #pragma unroll
                for (int i = 0; i < 8; ++i) {
                    accv[i] = fmaf((float)h0[i], w0, accv[i]);
                    accv[i] = fmaf((float)h1[i], w1, accv[i]);
                }
            }
        }
        s += __shfl_xor(s, 1); s += __shfl_xor(s, 2); s += __shfl_xor(s, 4);
        inv = 1.0f / (s + 1e-16f);
    }
    half8 o;
    #pragma unroll
    for (int i = 0; i < 8; ++i)
        o[i] = (_Float16)fmaxf(accv[i] * inv, 0.f);
    // swizzled 16B write: byte = grp*128 + ((l*16) ^ ((grp&7)<<4))
    const int hoff = (grp * 128 + ((l * 16) ^ ((grp & 7) << 4))) >> 1;
    *reinterpret_cast<half8*>(ts + hoff) = o;
    __syncthreads();
}

// swizzled LDS A-frag load: byte addr = row*128 + kb, kb multiple of 16
__device__ __forceinline__ half8 ts_afrag(const _Float16* ts, int row, int kb) {
    return *reinterpret_cast<const half8*>(ts + ((row * 128 + (kb ^ ((row & 7) << 4))) >> 1));
}

// mid layer: agg(layer0) -> relu -> @W1 -> XH1 + AL1/AR1
__global__ void agg_gemm_mid(const int2* __restrict__ rr, const int* __restrict__ csr,
                             const float* __restrict__ AL0, const float* __restrict__ AR0,
                             const _Float16* __restrict__ XH0,
                             const _Float16* __restrict__ W1T,
                             const float* __restrict__ al1w, const float* __restrict__ ar1w,
                             _Float16* __restrict__ XH1, float* __restrict__ AL1,
                             float* __restrict__ AR1, int N) {
    __shared__ _Float16 ts[16 * 64];
    const int nb = blockIdx.x * 16;
    agg_phase(rr, csr, AL0, AR0, XH0, ts, nb, N);
    if (threadIdx.x >= 64) return;            // GEMM tail: wave 0 only

    const int lane = threadIdx.x;
    const int idx16 = lane & 15, g = lane >> 4;
    float alv[4], arv[4];
    #pragma unroll
    for (int n = 0; n < 4; ++n) { alv[n] = al1w[n * 16 + idx16]; arv[n] = ar1w[n * 16 + idx16]; }

    float4v acc[4];
    #pragma unroll
    for (int n = 0; n < 4; ++n) acc[n] = float4v{0.f, 0.f, 0.f, 0.f};
    #pragma unroll
    for (int ks = 0; ks < 2; ++ks) {
        const half8 a = ts_afrag(ts, idx16, ks * 64 + g * 16);
        const int k0 = ks * 32 + g * 8;
        #pragma unroll
        for (int n = 0; n < 4; ++n) {
            const half8 b = *reinterpret_cast<const half8*>(W1T + (size_t)(n * 16 + idx16) * 64 + k0);
            acc[n] = __builtin_amdgcn_mfma_f32_16x16x32_f16(a, b, acc[n], 0, 0, 0);
        }
    }
    #pragma unroll
    for (int r = 0; r < 4; ++r) {
        const int row = nb + g * 4 + r;
        if (row < N) {
            float pl = 0.f, pr = 0.f;
            #pragma unroll
            for (int n = 0; n < 4; ++n) {
                float vv = acc[n][r];
                XH1[(size_t)row * 64 + n * 16 + idx16] = (_Float16)vv;
                pl = fmaf(vv, alv[n], pl);
                pr = fmaf(vv, arv[n], pr);
            }
            pl += __shfl_xor(pl, 1); pr += __shfl_xor(pr, 1);
            pl += __shfl_xor(pl, 2); pr += __shfl_xor(pr, 2);
            pl += __shfl_xor(pl, 4); pr += __shfl_xor(pr, 4);
            pl += __shfl_xor(pl, 8); pr += __shfl_xor(pr, 8);
            if (idx16 == 0) { AL1[row] = pl; AR1[row] = pr; }
        }
    }
}

// final layer: agg(layer1) -> relu -> @Wp1+bp1 -> @Wp2+bp2 -> OUT
__global__ void agg_post(const int2* __restrict__ rr, const int* __restrict__ csr,
                         const float* __restrict__ AL1, const float* __restrict__ AR1,
                         const _Float16* __restrict__ XH1,
                         const _Float16* __restrict__ Wp1T, const float* __restrict__ bp1,
                         const _Float16* __restrict__ Wp2T, const float* __restrict__ bp2,
                         float* __restrict__ OUT, int N) {
    __shared__ _Float16 ts[16 * 64];
    __shared__ _Float16 tls[16][72];
    const int nb = blockIdx.x * 16;
    agg_phase(rr, csr, AL1, AR1, XH1, ts, nb, N);
    if (threadIdx.x >= 64) return;            // GEMM tail: wave 0 only

    const int lane = threadIdx.x;
    const int idx16 = lane & 15, g = lane >> 4;

    float4v acc1[4];
    #pragma unroll
    for (int n = 0; n < 4; ++n) acc1[n] = float4v{0.f, 0.f, 0.f, 0.f};
    #pragma unroll
    for (int ks = 0; ks < 2; ++ks) {
        const half8 a = ts_afrag(ts, idx16, ks * 64 + g * 16);
        const int k0 = ks * 32 + g * 8;
        #pragma unroll
        for (int n = 0; n < 4; ++n) {
            const half8 b = *reinterpret_cast<const half8*>(Wp1T + (size_t)(n * 16 + idx16) * 64 + k0);
            acc1[n] = __builtin_amdgcn_mfma_f32_16x16x32_f16(a, b, acc1[n], 0, 0, 0);
        }
    }
    // t = acc1 + bp1 -> wave-local LDS transpose to A-frag layout
    #pragma unroll
    for (int r = 0; r < 4; ++r)
        #pragma unroll
        for (int n = 0; n < 4; ++n)
            tls[g * 4 + r][n * 16 + idx16] = (_Float16)(acc1[n][r] + bp1[n * 16 + idx16]);

    float4v acc2[4];
    #pragma unroll
    for (int n = 0; n < 4; ++n) acc2[n] = float4v{0.f, 0.f, 0.f, 0.f};
    #pragma unroll
    for (int ks = 0; ks < 2; ++ks) {
        const int k0 = ks * 32 + g * 8;
        const half8 a = *reinterpret_cast<const half8*>(&tls[idx16][k0]);
        #pragma unroll
        for (int n = 0; n < 4; ++n) {
            const half8 b = *reinterpret_cast<const half8*>(Wp2T + (size_t)(n * 16 + idx16) * 64 + k0);
            acc2[n] = __builtin_amdgcn_mfma_f32_16x16x32_f16(a, b, acc2[n], 0, 0, 0);
        }
    }
    #pragma unroll
    for (int r = 0; r < 4; ++r) {
        const int row = nb + g * 4 + r;
        if (row < N) {
            #pragma unroll
            for (int n = 0; n < 4; ++n)
                OUT[(size_t)row * 64 + n * 16 + idx16] = acc2[n][r] + bp2[n * 16 + idx16];
        }
    }
}

extern "C" void kernel_launch(void* const* d_in, const int* in_sizes, int n_in,
                              void* d_out, int out_size, void* d_ws, size_t ws_size,
                              hipStream_t stream) {
    const float* x   = (const float*)d_in[0];
    const int*   ei  = (const int*)d_in[1];
    const float* W0  = (const float*)d_in[2];
    const float* al0 = (const float*)d_in[3];
    const float* ar0 = (const float*)d_in[4];
    const float* W1  = (const float*)d_in[5];
    const float* al1 = (const float*)d_in[6];
    const float* ar1 = (const float*)d_in[7];
    const float* Wp1 = (const float*)d_in[8];
    const float* bp1 = (const float*)d_in[9];
    const float* Wp2 = (const float*)d_in[10];
    const float* bp2 = (const float*)d_in[11];
    float* out = (float*)d_out;

    const int N = in_sizes[0] / 128;   // 100000
    const int E = in_sizes[1] / 2;     // 1600000
    const int* src = ei;
    const int* dst = ei + E;
    const int NB = (N + 255) >> 8;     // 391 buckets

    // workspace layout (16B-aligned chunks)
    char* w = (char*)d_ws;
    _Float16* XH0  = (_Float16*)w;     w += sizeof(_Float16) * (size_t)N * 64;
    _Float16* XH1  = (_Float16*)w;     w += sizeof(_Float16) * (size_t)N * 64;
    float*  AL0    = (float*)w;        w += sizeof(float) * N;
    float*  AR0    = (float*)w;        w += sizeof(float) * N;
    float*  AL1    = (float*)w;        w += sizeof(float) * N;
    float*  AR1    = (float*)w;        w += sizeof(float) * N;
    int2*   rr     = (int2*)w;         w += sizeof(int2) * N;
    int*    csr    = (int*)w;          w += sizeof(int) * (size_t)NB * CAP;
    unsigned int* packed = (unsigned int*)w; w += sizeof(unsigned int) * (size_t)NB * CAP;
    int*    cursor = (int*)w;          w += sizeof(int) * 512;
    _Float16* W0T  = (_Float16*)w;     w += sizeof(_Float16) * 128 * 64;
    _Float16* W1T  = (_Float16*)w;     w += sizeof(_Float16) * 64 * 64;
    _Float16* Wp1T = (_Float16*)w;     w += sizeof(_Float16) * 64 * 64;
    _Float16* Wp2T = (_Float16*)w;

    dim3 blk(256);
    dim3 blk128(128);
    const int gn64 = (N + 63) / 64;
    const int gn16 = (N + 15) / 16;
    const int geb  = (E + 4095) / 4096;

    // ---- setup (weights fp16-transpose + cursor init) ----
    setup_misc<<<5, blk, 0, stream>>>(W0, W1, Wp1, Wp2, W0T, W1T, Wp1T, Wp2T,
                                      cursor, NB);

    // ---- bin edges into bucket regions (LDS-staged, coalesced flush) ----
    bin_staged<<<geb, blk, 0, stream>>>(src, dst, cursor, packed, E, NB);

    // ---- per-bucket counting sort overlapped with layer-0 GEMM ----
    sort_and_gemm0<<<NB + gn64, blk, 0, stream>>>(packed, cursor, csr, rr,
                                                  x, W0T, al0, ar0, XH0, AL0, AR0,
                                                  N, NB);

    // ---- fused: aggregate0 -> relu -> @W1 -> XH1/AL1/AR1 ----
    agg_gemm_mid<<<gn16, blk128, 0, stream>>>(rr, csr, AL0, AR0, XH0,
                                              W1T, al1, ar1, XH1, AL1, AR1, N);

    // ---- fused: aggregate1 -> relu -> post-MP -> out ----
    agg_post<<<gn16, blk128, 0, stream>>>(rr, csr, AL1, AR1, XH1,
                                          Wp1T, bp1, Wp2T, bp2, out, N);
}

// Round 18
// 141.454 us; speedup vs baseline: 1.0337x; 1.0337x over previous
//
#include <hip/hip_runtime.h>
#include <math.h>

#define NEG_SLOPE 0.2f
#define CAP 8192      // padded bucket capacity (mean fill 4096, sd ~64)

typedef _Float16 half8 __attribute__((ext_vector_type(8)));
typedef _Float16 half4v __attribute__((ext_vector_type(4)));
typedef float float4v __attribute__((ext_vector_type(4)));

// ---------------------------------------------------- setup: prep_wt + cursor
__global__ void setup_misc(const float* __restrict__ W0, const float* __restrict__ W1,
                           const float* __restrict__ Wp1, const float* __restrict__ Wp2,
                           _Float16* __restrict__ W0T, _Float16* __restrict__ W1T,
                           _Float16* __restrict__ Wp1T, _Float16* __restrict__ Wp2T,
                           int* __restrict__ cursor, int NB) {
    const int tid = threadIdx.x;
    if (blockIdx.x == 4) {
        for (int t = tid; t < NB; t += 256) cursor[t] = t * CAP;
        return;
    }
    __shared__ float lds[128 * 64];
    const float* src; _Float16* dstp; int K;
    switch (blockIdx.x) {
        case 0: src = W0;  dstp = W0T;  K = 128; break;
        case 1: src = W1;  dstp = W1T;  K = 64;  break;
        case 2: src = Wp1; dstp = Wp1T; K = 64;  break;
        default: src = Wp2; dstp = Wp2T; K = 64; break;
    }
    for (int i = tid; i < K * 64; i += 256) lds[i] = src[i];
    __syncthreads();
    for (int i = tid; i < K * 64; i += 256) {
        int n = i / K, k = i % K;
        dstp[i] = (_Float16)lds[k * 64 + n];
    }
}

// ------------- bin edges into bucket regions, LDS-staged coalesced writes ----
__global__ void bin_staged(const int* __restrict__ src, const int* __restrict__ dst,
                           int* __restrict__ cursor, unsigned int* __restrict__ packed,
                           int E, int NB) {
    __shared__ unsigned int sval[4096];
    __shared__ unsigned int saddr[4096];
    __shared__ int h[512], hcur[512], gb[512];
    __shared__ int stot;
    const int tid = threadIdx.x;
    if (tid == 0) stot = 0;
    for (int t = tid; t < NB; t += 256) h[t] = 0;
    __syncthreads();
    const int base = blockIdx.x * 4096;
    const int lim = min(base + 4096, E);
    int dreg[16], sreg[16];
    int cnt = 0;
    for (int i = base + tid; i < lim; i += 256) {
        dreg[cnt] = dst[i];
        sreg[cnt] = src[i];
        ++cnt;
    }
    for (int k = 0; k < cnt; ++k) atomicAdd(&h[dreg[k] >> 8], 1);
    __syncthreads();
    for (int t = tid; t < NB; t += 256) {
        int c = h[t];
        if (c) {
            int l = atomicAdd(&stot, c);          // block-local region (order-free)
            hcur[t] = l;
            gb[t] = atomicAdd(&cursor[t], c) - l; // gaddr = gb[bucket] + pos
        }
    }
    __syncthreads();
    for (int k = 0; k < cnt; ++k) {
        const int d = dreg[k];
        const int b = d >> 8;
        const int pos = atomicAdd(&hcur[b], 1);
        sval[pos] = ((unsigned int)(d & 255) << 24) | (unsigned int)sreg[k];
        saddr[pos] = (unsigned int)(gb[b] + pos);
    }
    __syncthreads();
    const int tot = stot;
    for (int j = tid; j < tot; j += 256)
        packed[saddr[j]] = sval[j];               // consecutive j -> coalesced runs
}

// ---------------- fused: bucket_sort (blocks<NB) | gemm0 (independent work)
// sort_body stages the bucket's packed data in LDS once (single global read);
// hist + scatter then run from LDS.
__device__ __forceinline__ void sort_body(const unsigned int* __restrict__ packed,
                                          const int* __restrict__ cursor,
                                          int* __restrict__ csr, int2* __restrict__ rr,
                                          int N, int b) {
    __shared__ unsigned int sp[CAP];          // 32 KB staged bucket
    __shared__ int hist[256], cur[256];
    __shared__ int wsum[4], woff[4];
    const int tid = threadIdx.x, wid = tid >> 6, lane = tid & 63;
    const int beg = b * CAP;
    const int end = cursor[b];                 // fill end of this bucket
    const int fill = end - beg;
    hist[tid] = 0;
    for (int i = tid; i < fill; i += 256)
        sp[i] = packed[beg + i];
    __syncthreads();
    for (int i = tid; i < fill; i += 256)
        atomicAdd(&hist[sp[i] >> 24], 1);
    __syncthreads();
    int v = hist[tid];
    int x = v;
    #pragma unroll
    for (int off = 1; off < 64; off <<= 1) {
        int t = __shfl_up(x, off);
        if (lane >= off) x += t;
    }
    if (lane == 63) wsum[wid] = x;
    __syncthreads();
    if (tid == 0) {
        int acc = 0;
        #pragma unroll
        for (int w = 0; w < 4; ++w) { woff[w] = acc; acc += wsum[w]; }
    }
    __syncthreads();
    int excl = woff[wid] + x - v;
    int node = (b << 8) + tid;
    if (node < N) rr[node] = make_int2(beg + excl, v);
    cur[tid] = excl;
    __syncthreads();
    for (int i = tid; i < fill; i += 256) {
        unsigned int p = sp[i];
        int pos = atomicAdd(&cur[p >> 24], 1);
        csr[beg + pos] = (int)(p & 0xFFFFFFu);
    }
}

__device__ __forceinline__ void gemm0_body(const float* __restrict__ X,
                                           const _Float16* __restrict__ WT,
                                           const float* __restrict__ alw,
                                           const float* __restrict__ arw,
                                           _Float16* __restrict__ XH,
                                           float* __restrict__ AL, float* __restrict__ AR,
                                           int N, int bid) {
    const int wid = threadIdx.x >> 6, lane = threadIdx.x & 63;
    const int rowbase = bid * 64 + wid * 16;
    const int idx16 = lane & 15;
    const int g = lane >> 4;
    const int mrow = rowbase + idx16;
    const bool mvalid = (mrow < N);

    float4v acc[4];
    #pragma unroll
    for (int n = 0; n < 4; ++n) acc[n] = float4v{0.f, 0.f, 0.f, 0.f};

    #pragma unroll
    for (int ks = 0; ks < 4; ++ks) {           // K = 128
        const int k0 = ks * 32 + g * 8;
        half8 a = {};
        if (mvalid) {
            const float* xp = X + (size_t)mrow * 128 + k0;
            float4v lo = *reinterpret_cast<const float4v*>(xp);
            float4v hi = *reinterpret_cast<const float4v*>(xp + 4);
            #pragma unroll
            for (int i = 0; i < 4; ++i) {
                a[i] = (_Float16)lo[i];
                a[i + 4] = (_Float16)hi[i];
            }
        }
        #pragma unroll
        for (int n = 0; n < 4; ++n) {
            const half8 b = *reinterpret_cast<const half8*>(WT + (size_t)(n * 16 + idx16) * 128 + k0);
            acc[n] = __builtin_amdgcn_mfma_f32_16x16x32_f16(a, b, acc[n], 0, 0, 0);
        }
    }

    float alv[4], arv[4];
    #pragma unroll
    for (int n = 0; n < 4; ++n) { alv[n] = alw[n * 16 + idx16]; arv[n] = arw[n * 16 + idx16]; }
    #pragma unroll
    for (int r = 0; r < 4; ++r) {
        const int row = rowbase + g * 4 + r;
        if (row < N) {
            float pl = 0.f, pr = 0.f;
            #pragma unroll
            for (int n = 0; n < 4; ++n) {
                float vv = acc[n][r];
                XH[(size_t)row * 64 + n * 16 + idx16] = (_Float16)vv;
                pl = fmaf(vv, alv[n], pl);
                pr = fmaf(vv, arv[n], pr);
            }
            pl += __shfl_xor(pl, 1); pr += __shfl_xor(pr, 1);
            pl += __shfl_xor(pl, 2); pr += __shfl_xor(pr, 2);
            pl += __shfl_xor(pl, 4); pr += __shfl_xor(pr, 4);
            pl += __shfl_xor(pl, 8); pr += __shfl_xor(pr, 8);
            if (idx16 == 0) { AL[row] = pl; AR[row] = pr; }
        }
    }
}

__global__ void sort_and_gemm0(const unsigned int* __restrict__ packed,
                               const int* __restrict__ cursor,
                               int* __restrict__ csr, int2* __restrict__ rr,
                               const float* __restrict__ X,
                               const _Float16* __restrict__ W0T,
                               const float* __restrict__ alw, const float* __restrict__ arw,
                               _Float16* __restrict__ XH0, float* __restrict__ AL0,
                               float* __restrict__ AR0, int N, int NB) {
    if ((int)blockIdx.x < NB)
        sort_body(packed, cursor, csr, rr, N, blockIdx.x);
    else
        gemm0_body(X, W0T, alw, arw, XH0, AL0, AR0, N, blockIdx.x - NB);
}

// ============================== fused aggregate -> relu -> GEMM kernels ====
// Block = 128 threads (2 waves), 16 nodes: one node per 8-LANE group
// (lane = 8 channels, half8 16B gathers -> 8 rows in flight per wave-load).
// R16's best-measured structure. Result (relu'd, normalized, fp16) -> LDS
// ts[16][64], XOR-swizzled. One barrier (2 waves); wave 0 runs the GEMM
// tail (16-row m-tile), wave 1 returns.

__device__ __forceinline__ void agg_phase(const int2* __restrict__ rr,
                                          const int* __restrict__ csr,
                                          const float* __restrict__ ALp,
                                          const float* __restrict__ ARp,
                                          const _Float16* __restrict__ XHp,
                                          _Float16* ts, int nb, int N) {
    const int tid = threadIdx.x;
    const int l = tid & 7, grp = tid >> 3;       // 16 groups of 8 lanes
    const int node = nb + grp;
    float accv[8] = {0.f, 0.f, 0.f, 0.f, 0.f, 0.f, 0.f, 0.f};
    float inv = 0.0f;
    if (node < N) {
        const int2 r = rr[node];
        const int beg = r.x, end = r.x + r.y;
        const float ar = ARp[node];
        float s = 0.f;
        for (int cbeg = beg; cbeg < end; cbeg += 8) {
            const int e = cbeg + l;
            const bool valid = (e < end);
            const int sidx = valid ? csr[e] : 0;
            float a = ALp[sidx] + ar;
            a = (a >= 0.0f) ? a : NEG_SLOPE * a;
            const float ex = valid ? __expf(a) : 0.0f;
            s += ex;
            #pragma unroll
            for (int j = 0; j < 8; ++j) {
                const float wgt = __shfl(ex, j, 8);
                const int si = __shfl(sidx, j, 8);
                const half8 h = *reinterpret_cast<const half8*>(XHp + (size_t)si * 64 + l * 8);
                #pragma unroll
                for (int i = 0; i < 8; ++i)
                    accv[i] = fmaf((float)h[i], wgt, accv[i]);
            }
        }
        s += __shfl_xor(s, 1); s += __shfl_xor(s, 2); s += __shfl_xor(s, 4);
        inv = 1.0f / (s + 1e-16f);
    }
    half8 o;
    #pragma unroll
    for (int i = 0; i < 8; ++i)
        o[i] = (_Float16)fmaxf(accv[i] * inv, 0.f);
    // swizzled 16B write: byte = grp*128 + ((l*16) ^ ((grp&7)<<4))
    const int hoff = (grp * 128 + ((l * 16) ^ ((grp & 7) << 4))) >> 1;
    *reinterpret_cast<half8*>(ts + hoff) = o;
    __syncthreads();
}

// swizzled LDS A-frag load: byte addr = row*128 + kb, kb multiple of 16
__device__ __forceinline__ half8 ts_afrag(const _Float16* ts, int row, int kb) {
    return *reinterpret_cast<const half8*>(ts + ((row * 128 + (kb ^ ((row & 7) << 4))) >> 1));
}

// mid layer: agg(layer0) -> relu -> @W1 -> XH1 + AL1/AR1
__global__ void agg_gemm_mid(const int2* __restrict__ rr, const int* __restrict__ csr,
                             const float* __restrict__ AL0, const float* __restrict__ AR0,
                             const _Float16* __restrict__ XH0,
                             const _Float16* __restrict__ W1T,
                             const float* __restrict__ al1w, const float* __restrict__ ar1w,
                             _Float16* __restrict__ XH1, float* __restrict__ AL1,
                             float* __restrict__ AR1, int N) {
    __shared__ _Float16 ts[16 * 64];
    const int nb = blockIdx.x * 16;
    agg_phase(rr, csr, AL0, AR0, XH0, ts, nb, N);
    if (threadIdx.x >= 64) return;            // GEMM tail: wave 0 only

    const int lane = threadIdx.x;
    const int idx16 = lane & 15, g = lane >> 4;
    float alv[4], arv[4];
    #pragma unroll
    for (int n = 0; n < 4; ++n) { alv[n] = al1w[n * 16 + idx16]; arv[n] = ar1w[n * 16 + idx16]; }

    float4v acc[4];
    #pragma unroll
    for (int n = 0; n < 4; ++n) acc[n] = float4v{0.f, 0.f, 0.f, 0.f};
    #pragma unroll
    for (int ks = 0; ks < 2; ++ks) {
        const half8 a = ts_afrag(ts, idx16, ks * 64 + g * 16);
        const int k0 = ks * 32 + g * 8;
        #pragma unroll
        for (int n = 0; n < 4; ++n) {
            const half8 b = *reinterpret_cast<const half8*>(W1T + (size_t)(n * 16 + idx16) * 64 + k0);
            acc[n] = __builtin_amdgcn_mfma_f32_16x16x32_f16(a, b, acc[n], 0, 0, 0);
        }
    }
    #pragma unroll
    for (int r = 0; r < 4; ++r) {
        const int row = nb + g * 4 + r;
        if (row < N) {
            float pl = 0.f, pr = 0.f;
            #pragma unroll
            for (int n = 0; n < 4; ++n) {
                float vv = acc[n][r];
                XH1[(size_t)row * 64 + n * 16 + idx16] = (_Float16)vv;
                pl = fmaf(vv, alv[n], pl);
                pr = fmaf(vv, arv[n], pr);
            }
            pl += __shfl_xor(pl, 1); pr += __shfl_xor(pr, 1);
            pl += __shfl_xor(pl, 2); pr += __shfl_xor(pr, 2);
            pl += __shfl_xor(pl, 4); pr += __shfl_xor(pr, 4);
            pl += __shfl_xor(pl, 8); pr += __shfl_xor(pr, 8);
            if (idx16 == 0) { AL1[row] = pl; AR1[row] = pr; }
        }
    }
}

// final layer: agg(layer1) -> relu -> @Wp1+bp1 -> @Wp2+bp2 -> OUT
__global__ void agg_post(const int2* __restrict__ rr, const int* __restrict__ csr,
                         const float* __restrict__ AL1, const float* __restrict__ AR1,
                         const _Float16* __restrict__ XH1,
                         const _Float16* __restrict__ Wp1T, const float* __restrict__ bp1,
                         const _Float16* __restrict__ Wp2T, const float* __restrict__ bp2,
                         float* __restrict__ OUT, int N) {
    __shared__ _Float16 ts[16 * 64];
    __shared__ _Float16 tls[16][72];
    const int nb = blockIdx.x * 16;
    agg_phase(rr, csr, AL1, AR1, XH1, ts, nb, N);
    if (threadIdx.x >= 64) return;            // GEMM tail: wave 0 only

    const int lane = threadIdx.x;
    const int idx16 = lane & 15, g = lane >> 4;

    float4v acc1[4];
    #pragma unroll
    for (int n = 0; n < 4; ++n) acc1[n] = float4v{0.f, 0.f, 0.f, 0.f};
    #pragma unroll
    for (int ks = 0; ks < 2; ++ks) {
        const half8 a = ts_afrag(ts, idx16, ks * 64 + g * 16);
        const int k0 = ks * 32 + g * 8;
        #pragma unroll
        for (int n = 0; n < 4; ++n) {
            const half8 b = *reinterpret_cast<const half8*>(Wp1T + (size_t)(n * 16 + idx16) * 64 + k0);
            acc1[n] = __builtin_amdgcn_mfma_f32_16x16x32_f16(a, b, acc1[n], 0, 0, 0);
        }
    }
    // t = acc1 + bp1 -> wave-local LDS transpose to A-frag layout
    #pragma unroll
    for (int r = 0; r < 4; ++r)
        #pragma unroll
        for (int n = 0; n < 4; ++n)
            tls[g * 4 + r][n * 16 + idx16] = (_Float16)(acc1[n][r] + bp1[n * 16 + idx16]);

    float4v acc2[4];
    #pragma unroll
    for (int n = 0; n < 4; ++n) acc2[n] = float4v{0.f, 0.f, 0.f, 0.f};
    #pragma unroll
    for (int ks = 0; ks < 2; ++ks) {
        const int k0 = ks * 32 + g * 8;
        const half8 a = *reinterpret_cast<const half8*>(&tls[idx16][k0]);
        #pragma unroll
        for (int n = 0; n < 4; ++n) {
            const half8 b = *reinterpret_cast<const half8*>(Wp2T + (size_t)(n * 16 + idx16) * 64 + k0);
            acc2[n] = __builtin_amdgcn_mfma_f32_16x16x32_f16(a, b, acc2[n], 0, 0, 0);
        }
    }
    #pragma unroll
    for (int r = 0; r < 4; ++r) {
        const int row = nb + g * 4 + r;
        if (row < N) {
            #pragma unroll
            for (int n = 0; n < 4; ++n)
                OUT[(size_t)row * 64 + n * 16 + idx16] = acc2[n][r] + bp2[n * 16 + idx16];
        }
    }
}

extern "C" void kernel_launch(void* const* d_in, const int* in_sizes, int n_in,
                              void* d_out, int out_size, void* d_ws, size_t ws_size,
                              hipStream_t stream) {
    const float* x   = (const float*)d_in[0];
    const int*   ei  = (const int*)d_in[1];
    const float* W0  = (const float*)d_in[2];
    const float* al0 = (const float*)d_in[3];
    const float* ar0 = (const float*)d_in[4];
    const float* W1  = (const float*)d_in[5];
    const float* al1 = (const float*)d_in[6];
    const float* ar1 = (const float*)d_in[7];
    const float* Wp1 = (const float*)d_in[8];
    const float* bp1 = (const float*)d_in[9];
    const float* Wp2 = (const float*)d_in[10];
    const float* bp2 = (const float*)d_in[11];
    float* out = (float*)d_out;

    const int N = in_sizes[0] / 128;   // 100000
    const int E = in_sizes[1] / 2;     // 1600000
    const int* src = ei;
    const int* dst = ei + E;
    const int NB = (N + 255) >> 8;     // 391 buckets

    // workspace layout (16B-aligned chunks)
    char* w = (char*)d_ws;
    _Float16* XH0  = (_Float16*)w;     w += sizeof(_Float16) * (size_t)N * 64;
    _Float16* XH1  = (_Float16*)w;     w += sizeof(_Float16) * (size_t)N * 64;
    float*  AL0    = (float*)w;        w += sizeof(float) * N;
    float*  AR0    = (float*)w;        w += sizeof(float) * N;
    float*  AL1    = (float*)w;        w += sizeof(float) * N;
    float*  AR1    = (float*)w;        w += sizeof(float) * N;
    int2*   rr     = (int2*)w;         w += sizeof(int2) * N;
    int*    csr    = (int*)w;          w += sizeof(int) * (size_t)NB * CAP;
    unsigned int* packed = (unsigned int*)w; w += sizeof(unsigned int) * (size_t)NB * CAP;
    int*    cursor = (int*)w;          w += sizeof(int) * 512;
    _Float16* W0T  = (_Float16*)w;     w += sizeof(_Float16) * 128 * 64;
    _Float16* W1T  = (_Float16*)w;     w += sizeof(_Float16) * 64 * 64;
    _Float16* Wp1T = (_Float16*)w;     w += sizeof(_Float16) * 64 * 64;
    _Float16* Wp2T = (_Float16*)w;

    dim3 blk(256);
    dim3 blk128(128);
    const int gn64 = (N + 63) / 64;
    const int gn16 = (N + 15) / 16;
    const int geb  = (E + 4095) / 4096;

    // ---- setup (weights fp16-transpose + cursor init) ----
    setup_misc<<<5, blk, 0, stream>>>(W0, W1, Wp1, Wp2, W0T, W1T, Wp1T, Wp2T,
                                      cursor, NB);

    // ---- bin edges into bucket regions (LDS-staged, coalesced flush) ----
    bin_staged<<<geb, blk, 0, stream>>>(src, dst, cursor, packed, E, NB);

    // ---- per-bucket counting sort (LDS-staged) overlapped with layer-0 GEMM ----
    sort_and_gemm0<<<NB + gn64, blk, 0, stream>>>(packed, cursor, csr, rr,
                                                  x, W0T, al0, ar0, XH0, AL0, AR0,
                                                  N, NB);

    // ---- fused: aggregate0 -> relu -> @W1 -> XH1/AL1/AR1 ----
    agg_gemm_mid<<<gn16, blk128, 0, stream>>>(rr, csr, AL0, AR0, XH0,
                                              W1T, al1, ar1, XH1, AL1, AR1, N);

    // ---- fused: aggregate1 -> relu -> post-MP -> out ----
    agg_post<<<gn16, blk128, 0, stream>>>(rr, csr, AL1, AR1, XH1,
                                          Wp1T, bp1, Wp2T, bp2, out, N);
}